// Round 2
// baseline (417.364 us; speedup 1.0000x reference)
//
#include <hip/hip_runtime.h>
#include <cstdint>
#include <cstddef>

#define BATCH 8
#define FHh   32
#define FWw   256
#define NA    6
#define NANCH (FHh * FWw * NA)   // 49152
#define PRE_K 2000
#define POST_K 300
#define NBIN  65536
#define CAND_CAP 4096

// ---------------- workspace layout (bytes), total 5,988,864 ----------------
// scores  : [0, 1572864)                      BATCH*NANCH f32
// region A: [1572864, 5668864)  lifetime-split:
//    hist  : A+0       8*65536*4 = 2,097,152   (K0..K2)
//    cand  : A+2097152 8*4096*8  =   262,144   (K3..K4)
//    meta  : abs 3932160: cut[8], cnt[8]       (K2..K4)
//    supp  : A+0       8*2000*32*8 = 4,096,000 (K5..K6)
// pre_boxes : [5668864, 5924864)  BATCH*PRE_K float4
// pre_scores: [5924864, 5988864)  BATCH*PRE_K f32
#define WS_SC   0
#define WS_A    1572864
#define WS_CAND (WS_A + 2097152)
#define WS_META 3932160
#define WS_PB   5668864
#define WS_PS   5924864

// ---------------- K0: zero histogram + counters ----------------
__global__ void k_zero(unsigned int* __restrict__ hist, unsigned int* __restrict__ cnt) {
    int g = blockIdx.x * blockDim.x + threadIdx.x;
    if (g < BATCH * NBIN) hist[g] = 0u;
    if (g < BATCH) cnt[g] = 0u;
}

// ---------------- K1: fused softmax + 16-bit-key histogram ----------------
__global__ void k_softhist(const float* __restrict__ labels, float* __restrict__ scores,
                           unsigned int* __restrict__ hist) {
    int pos = blockIdx.x * blockDim.x + threadIdx.x;  // over BATCH*FH*FW
    if (pos >= BATCH * FHh * FWw) return;
    int b = pos / (FHh * FWw);
    const float* in = labels + (size_t)pos * NA;
    float v[NA];
    float m = in[0];
#pragma unroll
    for (int a = 0; a < NA; ++a) { v[a] = in[a]; m = fmaxf(m, v[a]); }
    float s = 0.0f;
#pragma unroll
    for (int a = 0; a < NA; ++a) { v[a] = expf(v[a] - m); s += v[a]; }
    float* o = scores + (size_t)pos * NA;
    unsigned int* hb = hist + (size_t)b * NBIN;
#pragma unroll
    for (int a = 0; a < NA; ++a) {
        float sc = v[a] / s;
        o[a] = sc;
        atomicAdd(&hb[__float_as_uint(sc) >> 16], 1u);  // fire-and-forget
    }
}

// ---------------- K2: per-batch find 16-bit cutoff bin ----------------
__global__ __launch_bounds__(1024) void k_cut(const unsigned int* __restrict__ hist,
                                              unsigned int* __restrict__ cut) {
    const int b = blockIdx.x;
    const int tid = threadIdx.x;
    const unsigned int* h = hist + (size_t)b * NBIN;
    const int base = NBIN - 1 - tid * 64;  // top bin of this thread's chunk
    unsigned int s = 0;
    for (int k = 0; k < 64; ++k) s += h[base - k];
    // block-wide scan in tid order (tid 0 = highest bins)
    const int lane = tid & 63, wid = tid >> 6;
    unsigned int inc = s;
#pragma unroll
    for (int d = 1; d < 64; d <<= 1) {
        unsigned int v = __shfl_up(inc, d);
        if (lane >= d) inc += v;
    }
    __shared__ unsigned int wtot[16];
    if (lane == 63) wtot[wid] = inc;
    __syncthreads();
    unsigned int woff = 0;
    for (int w = 0; w < 16; ++w) if (w < wid) woff += wtot[w];
    unsigned int excl = woff + inc - s;  // count strictly above this chunk
    if (excl < PRE_K && excl + s >= PRE_K) {
        unsigned int run = excl;
        for (int k = 0; k < 64; ++k) {
            run += h[base - k];
            if (run >= PRE_K) { cut[b] = (unsigned int)(base - k); break; }
        }
    }
}

// ---------------- K3: gather candidates (bits>>16 >= cut) ----------------
__global__ void k_gather(const float* __restrict__ scores, const unsigned int* __restrict__ cut,
                         unsigned long long* __restrict__ cand, unsigned int* __restrict__ cnt) {
    int g = blockIdx.x * blockDim.x + threadIdx.x;  // BATCH*NANCH
    if (g >= BATCH * NANCH) return;
    int b = g / NANCH;
    int idx = g - b * NANCH;
    unsigned int bits = __float_as_uint(scores[g]);
    if ((bits >> 16) >= cut[b]) {
        unsigned int p = atomicAdd(&cnt[b], 1u);
        if (p < CAND_CAP)
            cand[(size_t)b * CAND_CAP + p] =
                ((unsigned long long)bits << 32) | (unsigned int)(~idx);
    }
}

// ---------------- K4: per-batch bitonic sort 4096 + decode top-2000 ----------
__global__ __launch_bounds__(1024) void k_sortdec(
        const unsigned long long* __restrict__ cand, const unsigned int* __restrict__ cnt,
        const float* __restrict__ deltas, const float* __restrict__ anchors,
        float4* __restrict__ pre_boxes, float* __restrict__ pre_scores) {
    const int b = blockIdx.x;
    const int tid = threadIdx.x;
    __shared__ unsigned long long skey[CAND_CAP];
    unsigned int n = cnt[b]; if (n > CAND_CAP) n = CAND_CAP;
    const unsigned long long* cb = cand + (size_t)b * CAND_CAP;
    for (int i = tid; i < CAND_CAP; i += 1024) skey[i] = (i < (int)n) ? cb[i] : 0ull;
    __syncthreads();
    for (int k = 2; k <= CAND_CAP; k <<= 1) {
        for (int j = k >> 1; j > 0; j >>= 1) {
            for (int i = tid; i < CAND_CAP; i += 1024) {
                int p = i ^ j;
                if (p > i) {
                    unsigned long long a = skey[i], c = skey[p];
                    bool up = ((i & k) == 0);  // descending block
                    if ((a < c) == up) { skey[i] = c; skey[p] = a; }
                }
            }
            __syncthreads();
        }
    }
    // decode the selected 2000 boxes (same op order as reference)
    for (int t = tid; t < PRE_K; t += 1024) {
        unsigned long long key = skey[t];
        int idx = (int)(~(unsigned int)key);
        float score = __uint_as_float((unsigned int)(key >> 32));
        const float* anc = anchors + (size_t)idx * 4;
        const float* del = deltas + ((size_t)b * NANCH + idx) * 4;
        float a0 = anc[0], a1 = anc[1], a2 = anc[2], a3 = anc[3];
        float ah = a2 - a0, aw = a3 - a1;
        float acy = a0 + 0.5f * ah, acx = a1 + 0.5f * aw;
        float d0 = del[0] * 0.1f, d1 = del[1] * 0.1f;
        float d2 = del[2] * 0.2f, d3 = del[3] * 0.2f;
        float bh = expf(d2) * ah, bw = expf(d3) * aw;
        float bcy = d0 * ah + acy, bcx = d1 * aw + acx;
        float y1 = bcy - 0.5f * bh, x1 = bcx - 0.5f * bw;
        pre_boxes[(size_t)b * PRE_K + t] = make_float4(y1, x1, y1 + bh, x1 + bw);
        pre_scores[(size_t)b * PRE_K + t] = score;
    }
}

// ---------------- K5: suppression bit-matrix (LDS-staged cols) ----------------
// grid (32 colwords, 32 rowblocks, BATCH), 64 threads = 64 rows
__global__ __launch_bounds__(64) void k_iou(const float4* __restrict__ pre_boxes,
                                            unsigned long long* __restrict__ supp) {
    const int cb = blockIdx.x;   // col word 0..31
    const int rb = blockIdx.y;   // row block 0..31
    const int b  = blockIdx.z;
    const int lane = threadIdx.x;
    const int i = rb * 64 + lane;
    const int j0 = cb * 64;
    if (cb < rb) {  // every j in word <= every i in block -> zero word
        if (i < PRE_K) supp[((size_t)b * PRE_K + i) * 32 + cb] = 0ull;
        return;
    }
    __shared__ float4 sbox[64];
    const float4* boxes = pre_boxes + (size_t)b * PRE_K;
    int j = j0 + lane;
    sbox[lane] = (j < PRE_K) ? boxes[j] : make_float4(0.f, 0.f, 0.f, 0.f);
    __syncthreads();
    if (i >= PRE_K) return;
    float4 bi = boxes[i];
    float area_i = (bi.z - bi.x) * (bi.w - bi.y);
    unsigned long long bits = 0ull;
    const int tmax = (PRE_K - j0 < 64) ? (PRE_K - j0) : 64;
    for (int t = 0; t < tmax; ++t) {
        int jj = j0 + t;
        if (jj <= i) continue;
        float4 bj = sbox[t];
        float iy1 = fmaxf(bi.x, bj.x), ix1 = fmaxf(bi.y, bj.y);
        float iy2 = fminf(bi.z, bj.z), ix2 = fminf(bi.w, bj.w);
        float inter = fmaxf(iy2 - iy1, 0.0f) * fmaxf(ix2 - ix1, 0.0f);
        float area_j = (bj.z - bj.x) * (bj.w - bj.y);
        float uni = area_i + area_j - inter;
        float iou = inter / fmaxf(uni, 1e-8f);
        if (iou > 0.7f) bits |= (1ull << t);
    }
    supp[((size_t)b * PRE_K + i) * 32 + cb] = bits;
}

// ---------------- K6: serial greedy reduce + compact + outputs ----------------
#define CHNK 16
__global__ void k_final(const unsigned long long* __restrict__ supp,
                        const float4* __restrict__ pre_boxes,
                        const float* __restrict__ pre_scores,
                        float* __restrict__ out) {
    const int b = blockIdx.x;
    const int lane = threadIdx.x;
    float* ob = out + (size_t)b * POST_K * 4;
    float* os = out + (size_t)BATCH * POST_K * 4 + (size_t)b * POST_K;
    for (int t = lane; t < POST_K * 4; t += 64) ob[t] = 0.0f;
    for (int t = lane; t < POST_K; t += 64) os[t] = 0.0f;

    const unsigned long long* S = supp + (size_t)b * PRE_K * 32;
    const int lw = lane & 31;
    unsigned long long removed = 0ull;
    unsigned long long bufA[CHNK], bufB[CHNK];
#pragma unroll
    for (int c = 0; c < CHNK; ++c) bufA[c] = S[(size_t)c * 32 + lw];
    const int NCH = PRE_K / CHNK;  // 125
    for (int ch = 0; ch < NCH; ++ch) {
        const int base = ch * CHNK;
        if (ch + 1 < NCH) {
#pragma unroll
            for (int c = 0; c < CHNK; ++c)
                bufB[c] = S[(size_t)(base + CHNK + c) * 32 + lw];
        }
#pragma unroll
        for (int c = 0; c < CHNK; ++c) {
            const int i = base + c;
            const int wi = i >> 6;
            const int bi = i & 63;
            int cand = (int)((removed >> bi) & 1ull);
            int bit = __builtin_amdgcn_readlane(cand, wi);  // wi is wave-uniform
            if (bit == 0 && lane < 32) removed |= bufA[c];
        }
#pragma unroll
        for (int c = 0; c < CHNK; ++c) bufA[c] = bufB[c];
    }

    // compact kept rows in order -> first POST_K outputs
    unsigned long long kw = ~removed;
    if (lw == 31) kw &= 0xFFFFull;  // rows 1984..1999 only
    int cnt = (lane < 32) ? __builtin_popcountll(kw) : 0;
    int cum = cnt;
#pragma unroll
    for (int d = 1; d < 64; d <<= 1) {
        int v = __shfl_up(cum, d);
        if (lane >= d) cum += v;
    }
    int r = cum - cnt;  // exclusive prefix = output rank of first kept in word
    __syncthreads();    // order zero-fill stores before scatter stores
    if (lane < 32) {
        unsigned long long m = kw;
        while (m != 0ull && r < POST_K) {
            int t = __builtin_ctzll(m);
            m &= m - 1ull;
            int i = lw * 64 + t;
            float4 bx = pre_boxes[(size_t)b * PRE_K + i];
            ob[r * 4 + 0] = fminf(fmaxf(bx.x, 0.0f), 1.0f);
            ob[r * 4 + 1] = fminf(fmaxf(bx.y, 0.0f), 1.0f);
            ob[r * 4 + 2] = fminf(fmaxf(bx.z, 0.0f), 1.0f);
            ob[r * 4 + 3] = fminf(fmaxf(bx.w, 0.0f), 1.0f);
            os[r] = pre_scores[(size_t)b * PRE_K + i];
            ++r;
        }
    }
}

extern "C" void kernel_launch(void* const* d_in, const int* in_sizes, int n_in,
                              void* d_out, int out_size, void* d_ws, size_t ws_size,
                              hipStream_t stream) {
    const float* deltas  = (const float*)d_in[0];  // (8,32,256,24)
    const float* labels  = (const float*)d_in[1];  // (8,32,256,6)
    const float* anchors = (const float*)d_in[2];  // (49152,4)
    float* out = (float*)d_out;                    // 9600 box floats + 2400 scores

    char* ws = (char*)d_ws;
    float* scores          = (float*)(ws + WS_SC);
    unsigned int* hist     = (unsigned int*)(ws + WS_A);
    unsigned long long* cd = (unsigned long long*)(ws + WS_CAND);
    unsigned int* cutp     = (unsigned int*)(ws + WS_META);
    unsigned int* cntp     = cutp + 8;
    unsigned long long* sp = (unsigned long long*)(ws + WS_A);  // supp reuses A
    float4* pre_boxes      = (float4*)(ws + WS_PB);
    float* pre_scores      = (float*)(ws + WS_PS);

    k_zero<<<(BATCH * NBIN + 255) / 256, 256, 0, stream>>>(hist, cntp);
    k_softhist<<<(BATCH * FHh * FWw + 255) / 256, 256, 0, stream>>>(labels, scores, hist);
    k_cut<<<BATCH, 1024, 0, stream>>>(hist, cutp);
    k_gather<<<(BATCH * NANCH + 255) / 256, 256, 0, stream>>>(scores, cutp, cd, cntp);
    k_sortdec<<<BATCH, 1024, 0, stream>>>(cd, cntp, deltas, anchors, pre_boxes, pre_scores);
    k_iou<<<dim3(32, 32, BATCH), 64, 0, stream>>>(pre_boxes, sp);
    k_final<<<BATCH, 64, 0, stream>>>(sp, pre_boxes, pre_scores, out);
}

// Round 3
// 238.346 us; speedup vs baseline: 1.7511x; 1.7511x over previous
//
#include <hip/hip_runtime.h>
#include <cstdint>
#include <cstddef>

#define BATCH 8
#define FHh   32
#define FWw   256
#define NA    6
#define NANCH (FHh * FWw * NA)   // 49152
#define PRE_K 2000
#define POST_K 300
#define NBIN  65536
#define SEGS  192                // blocks per batch in k_gather (NANCH/256)
#define SKEYN 4096

// ---------------- workspace layout (bytes), total 5,675,520 ----------------
// [0, 1572864)      : scores (K1-K4); then pre_boxes [0,256000) +
//                     pre_scores [256000,320000) (K5-K7) — disjoint lifetime
// A=[1572864, 5668864): hist 2MB (K0-K3) -> cand 3,145,728 (K4-K5)
//                       -> supp 4,096,000 (K6-K7) — disjoint lifetimes
// [5668864, 5675008): counts 8*192 u32
// [5675008, 5675520): cut, padded 16 u32 (64B) per batch
#define WS_SC   0
#define WS_PB   0
#define WS_PS   256000
#define WS_A    1572864
#define WS_CNT  5668864
#define WS_CUT  5675008

// ---------------- K0: zero histogram ----------------
__global__ void k_zero(unsigned int* __restrict__ hist) {
    int g = blockIdx.x * blockDim.x + threadIdx.x;
    if (g < BATCH * NBIN) hist[g] = 0u;
}

// ---------------- K1: fused softmax + 16-bit-key histogram ----------------
__global__ void k_softhist(const float* __restrict__ labels, float* __restrict__ scores,
                           unsigned int* __restrict__ hist) {
    int pos = blockIdx.x * blockDim.x + threadIdx.x;  // over BATCH*FH*FW
    if (pos >= BATCH * FHh * FWw) return;
    int b = pos / (FHh * FWw);
    const float* in = labels + (size_t)pos * NA;
    float v[NA];
    float m = in[0];
#pragma unroll
    for (int a = 0; a < NA; ++a) { v[a] = in[a]; m = fmaxf(m, v[a]); }
    float s = 0.0f;
#pragma unroll
    for (int a = 0; a < NA; ++a) { v[a] = expf(v[a] - m); s += v[a]; }
    float* o = scores + (size_t)pos * NA;
    unsigned int* hb = hist + (size_t)b * NBIN;
#pragma unroll
    for (int a = 0; a < NA; ++a) {
        float sc = v[a] / s;
        o[a] = sc;
        atomicAdd(&hb[__float_as_uint(sc) >> 16], 1u);  // fire-and-forget
    }
}

// ---------------- K2: per-batch find 16-bit cutoff bin ----------------
__global__ __launch_bounds__(1024) void k_cut(const unsigned int* __restrict__ hist,
                                              unsigned int* __restrict__ cut) {
    const int b = blockIdx.x;
    const int tid = threadIdx.x;
    const unsigned int* h = hist + (size_t)b * NBIN;
    const int base = NBIN - 1 - tid * 64;  // top bin of this thread's chunk
    unsigned int s = 0;
    for (int k = 0; k < 64; ++k) s += h[base - k];
    const int lane = tid & 63, wid = tid >> 6;
    unsigned int inc = s;
#pragma unroll
    for (int d = 1; d < 64; d <<= 1) {
        unsigned int v = __shfl_up(inc, d);
        if (lane >= d) inc += v;
    }
    __shared__ unsigned int wtot[16];
    if (lane == 63) wtot[wid] = inc;
    __syncthreads();
    unsigned int woff = 0;
    for (int w = 0; w < 16; ++w) if (w < wid) woff += wtot[w];
    unsigned int excl = woff + inc - s;  // count strictly above this chunk
    if (excl < PRE_K && excl + s >= PRE_K) {
        unsigned int run = excl;
        for (int k = 0; k < 64; ++k) {
            run += h[base - k];
            if (run >= PRE_K) { cut[b * 16] = (unsigned int)(base - k); break; }
        }
    }
}

// ------- K3: atomic-free gather. block = (batch b, segment kb of 256 anchors);
//         ballot-rank within block, private output segment. -------------------
__global__ __launch_bounds__(256) void k_gather(
        const float* __restrict__ scores, const unsigned int* __restrict__ cut,
        unsigned long long* __restrict__ cand, unsigned int* __restrict__ counts) {
    const int blk = blockIdx.x;
    const int b = blk / SEGS, kb = blk - b * SEGS;
    const int tid = threadIdx.x;
    __shared__ unsigned int s_cut;
    __shared__ unsigned int s_wcnt[4];
    if (tid == 0) s_cut = cut[b * 16];
    __syncthreads();
    const int idx = kb * 256 + tid;                       // batch-local anchor
    const unsigned int bits = __float_as_uint(scores[(size_t)b * NANCH + idx]);
    const bool pass = (bits >> 16) >= s_cut;
    const unsigned long long m = __ballot(pass);
    const int lane = tid & 63, w = tid >> 6;
    if (lane == 0) s_wcnt[w] = (unsigned int)__popcll(m);
    __syncthreads();
    unsigned int pre = 0, tot = 0;
#pragma unroll
    for (int i = 0; i < 4; ++i) { unsigned int c = s_wcnt[i]; if (i < w) pre += c; tot += c; }
    if (pass) {
        unsigned int rank = pre + (unsigned int)__popcll(m & ((1ull << lane) - 1ull));
        cand[((size_t)b * SEGS + kb) * 256 + rank] =
            ((unsigned long long)bits << 32) | (unsigned int)(~idx);
    }
    if (tid == 0) counts[b * SEGS + kb] = tot;
}

// ---- K4: per-batch compact segments -> bitonic sort 4096 -> decode top-2000 --
__global__ __launch_bounds__(1024) void k_sortdec(
        const unsigned long long* __restrict__ cand, const unsigned int* __restrict__ counts,
        const float* __restrict__ deltas, const float* __restrict__ anchors,
        float4* __restrict__ pre_boxes, float* __restrict__ pre_scores) {
    const int b = blockIdx.x;
    const int tid = threadIdx.x;
    __shared__ unsigned long long skey[SKEYN];
    __shared__ unsigned int s_wsum[3];
    for (int i = tid; i < SKEYN; i += 1024) skey[i] = 0ull;

    // scan the 192 per-segment counts (3 waves)
    unsigned int v = (tid < SEGS) ? counts[b * SEGS + tid] : 0u;
    const int lane = tid & 63, wid = tid >> 6;
    unsigned int inc = v;
#pragma unroll
    for (int d = 1; d < 64; d <<= 1) {
        unsigned int t = __shfl_up(inc, d);
        if (lane >= d) inc += t;
    }
    if (wid < 3 && lane == 63) s_wsum[wid] = inc;
    __syncthreads();
    if (tid < SEGS) {
        unsigned int woff = 0;
        for (int i = 0; i < wid; ++i) woff += s_wsum[i];
        unsigned int off = woff + inc - v;  // exclusive prefix
        const unsigned long long* seg = cand + ((size_t)b * SEGS + tid) * 256;
        for (unsigned int k = 0; k < v; ++k) {
            unsigned int p = off + k;
            if (p < SKEYN) skey[p] = seg[k];
        }
    }
    __syncthreads();

    // bitonic sort 4096 descending
    for (int k = 2; k <= SKEYN; k <<= 1) {
        for (int j = k >> 1; j > 0; j >>= 1) {
            for (int i = tid; i < SKEYN; i += 1024) {
                int p = i ^ j;
                if (p > i) {
                    unsigned long long a = skey[i], c = skey[p];
                    bool up = ((i & k) == 0);
                    if ((a < c) == up) { skey[i] = c; skey[p] = a; }
                }
            }
            __syncthreads();
        }
    }

    // decode the selected 2000 boxes (same op order as reference)
    for (int t = tid; t < PRE_K; t += 1024) {
        unsigned long long key = skey[t];
        int idx = (int)(~(unsigned int)key);
        float score = __uint_as_float((unsigned int)(key >> 32));
        const float* anc = anchors + (size_t)idx * 4;
        const float* del = deltas + ((size_t)b * NANCH + idx) * 4;
        float a0 = anc[0], a1 = anc[1], a2 = anc[2], a3 = anc[3];
        float ah = a2 - a0, aw = a3 - a1;
        float acy = a0 + 0.5f * ah, acx = a1 + 0.5f * aw;
        float d0 = del[0] * 0.1f, d1 = del[1] * 0.1f;
        float d2 = del[2] * 0.2f, d3 = del[3] * 0.2f;
        float bh = expf(d2) * ah, bw = expf(d3) * aw;
        float bcy = d0 * ah + acy, bcx = d1 * aw + acx;
        float y1 = bcy - 0.5f * bh, x1 = bcx - 0.5f * bw;
        pre_boxes[(size_t)b * PRE_K + t] = make_float4(y1, x1, y1 + bh, x1 + bw);
        pre_scores[(size_t)b * PRE_K + t] = score;
    }
}

// ---------------- K5: suppression bit-matrix (LDS-staged cols) ----------------
__global__ __launch_bounds__(64) void k_iou(const float4* __restrict__ pre_boxes,
                                            unsigned long long* __restrict__ supp) {
    const int cb = blockIdx.x;   // col word 0..31
    const int rb = blockIdx.y;   // row block 0..31
    const int b  = blockIdx.z;
    const int lane = threadIdx.x;
    const int i = rb * 64 + lane;
    const int j0 = cb * 64;
    if (cb < rb) {
        if (i < PRE_K) supp[((size_t)b * PRE_K + i) * 32 + cb] = 0ull;
        return;
    }
    __shared__ float4 sbox[64];
    const float4* boxes = pre_boxes + (size_t)b * PRE_K;
    int j = j0 + lane;
    sbox[lane] = (j < PRE_K) ? boxes[j] : make_float4(0.f, 0.f, 0.f, 0.f);
    __syncthreads();
    if (i >= PRE_K) return;
    float4 bi = boxes[i];
    float area_i = (bi.z - bi.x) * (bi.w - bi.y);
    unsigned long long bits = 0ull;
    const int tmax = (PRE_K - j0 < 64) ? (PRE_K - j0) : 64;
    for (int t = 0; t < tmax; ++t) {
        int jj = j0 + t;
        if (jj <= i) continue;
        float4 bj = sbox[t];
        float iy1 = fmaxf(bi.x, bj.x), ix1 = fmaxf(bi.y, bj.y);
        float iy2 = fminf(bi.z, bj.z), ix2 = fminf(bi.w, bj.w);
        float inter = fmaxf(iy2 - iy1, 0.0f) * fmaxf(ix2 - ix1, 0.0f);
        float area_j = (bj.z - bj.x) * (bj.w - bj.y);
        float uni = area_i + area_j - inter;
        float iou = inter / fmaxf(uni, 1e-8f);
        if (iou > 0.7f) bits |= (1ull << t);
    }
    supp[((size_t)b * PRE_K + i) * 32 + cb] = bits;
}

// ---------------- K6: serial greedy reduce + compact + outputs ----------------
#define CHNK 16
__global__ void k_final(const unsigned long long* __restrict__ supp,
                        const float4* __restrict__ pre_boxes,
                        const float* __restrict__ pre_scores,
                        float* __restrict__ out) {
    const int b = blockIdx.x;
    const int lane = threadIdx.x;
    float* ob = out + (size_t)b * POST_K * 4;
    float* os = out + (size_t)BATCH * POST_K * 4 + (size_t)b * POST_K;
    for (int t = lane; t < POST_K * 4; t += 64) ob[t] = 0.0f;
    for (int t = lane; t < POST_K; t += 64) os[t] = 0.0f;

    const unsigned long long* S = supp + (size_t)b * PRE_K * 32;
    const int lw = lane & 31;
    unsigned long long removed = 0ull;
    unsigned long long bufA[CHNK], bufB[CHNK];
#pragma unroll
    for (int c = 0; c < CHNK; ++c) bufA[c] = S[(size_t)c * 32 + lw];
    const int NCH = PRE_K / CHNK;  // 125
    for (int ch = 0; ch < NCH; ++ch) {
        const int base = ch * CHNK;
        if (ch + 1 < NCH) {
#pragma unroll
            for (int c = 0; c < CHNK; ++c)
                bufB[c] = S[(size_t)(base + CHNK + c) * 32 + lw];
        }
#pragma unroll
        for (int c = 0; c < CHNK; ++c) {
            const int i = base + c;
            const int wi = i >> 6;
            const int bi = i & 63;
            int cand = (int)((removed >> bi) & 1ull);
            int bit = __builtin_amdgcn_readlane(cand, wi);  // wi is wave-uniform
            if (bit == 0 && lane < 32) removed |= bufA[c];
        }
#pragma unroll
        for (int c = 0; c < CHNK; ++c) bufA[c] = bufB[c];
    }

    unsigned long long kw = ~removed;
    if (lw == 31) kw &= 0xFFFFull;  // rows 1984..1999 only
    int cnt = (lane < 32) ? __builtin_popcountll(kw) : 0;
    int cum = cnt;
#pragma unroll
    for (int d = 1; d < 64; d <<= 1) {
        int v = __shfl_up(cum, d);
        if (lane >= d) cum += v;
    }
    int r = cum - cnt;
    __syncthreads();
    if (lane < 32) {
        unsigned long long m = kw;
        while (m != 0ull && r < POST_K) {
            int t = __builtin_ctzll(m);
            m &= m - 1ull;
            int i = lw * 64 + t;
            float4 bx = pre_boxes[(size_t)b * PRE_K + i];
            ob[r * 4 + 0] = fminf(fmaxf(bx.x, 0.0f), 1.0f);
            ob[r * 4 + 1] = fminf(fmaxf(bx.y, 0.0f), 1.0f);
            ob[r * 4 + 2] = fminf(fmaxf(bx.z, 0.0f), 1.0f);
            ob[r * 4 + 3] = fminf(fmaxf(bx.w, 0.0f), 1.0f);
            os[r] = pre_scores[(size_t)b * PRE_K + i];
            ++r;
        }
    }
}

extern "C" void kernel_launch(void* const* d_in, const int* in_sizes, int n_in,
                              void* d_out, int out_size, void* d_ws, size_t ws_size,
                              hipStream_t stream) {
    const float* deltas  = (const float*)d_in[0];
    const float* labels  = (const float*)d_in[1];
    const float* anchors = (const float*)d_in[2];
    float* out = (float*)d_out;

    char* ws = (char*)d_ws;
    float* scores          = (float*)(ws + WS_SC);
    unsigned int* hist     = (unsigned int*)(ws + WS_A);
    unsigned long long* cd = (unsigned long long*)(ws + WS_A);   // reuses hist
    unsigned long long* sp = (unsigned long long*)(ws + WS_A);   // reuses cand
    unsigned int* cntp     = (unsigned int*)(ws + WS_CNT);
    unsigned int* cutp     = (unsigned int*)(ws + WS_CUT);
    float4* pre_boxes      = (float4*)(ws + WS_PB);              // reuses scores
    float* pre_scores      = (float*)(ws + WS_PS);

    k_zero<<<(BATCH * NBIN + 255) / 256, 256, 0, stream>>>(hist);
    k_softhist<<<(BATCH * FHh * FWw + 255) / 256, 256, 0, stream>>>(labels, scores, hist);
    k_cut<<<BATCH, 1024, 0, stream>>>(hist, cutp);
    k_gather<<<BATCH * SEGS, 256, 0, stream>>>(scores, cutp, cd, cntp);
    k_sortdec<<<BATCH, 1024, 0, stream>>>(cd, cntp, deltas, anchors, pre_boxes, pre_scores);
    k_iou<<<dim3(32, 32, BATCH), 64, 0, stream>>>(pre_boxes, sp);
    k_final<<<BATCH, 64, 0, stream>>>(sp, pre_boxes, pre_scores, out);
}

// Round 4
// 206.997 us; speedup vs baseline: 2.0163x; 1.1514x over previous
//
#include <hip/hip_runtime.h>
#include <cstdint>
#include <cstddef>

#define BATCH 8
#define FHh   32
#define FWw   256
#define NA    6
#define NANCH (FHh * FWw * NA)   // 49152
#define PRE_K 2000
#define POST_K 300
#define NBIN  65536
#define SEGS  192                // blocks per batch in k_gather (NANCH/256)
#define SKEYN 4096

// ---------------- workspace layout (bytes), total 5,675,520 ----------------
// [0, 1572864)      : scores (K1-K4); then pre_boxes [0,256000) +
//                     pre_scores [256000,320000) (K5-K7) — disjoint lifetime
// A=[1572864, 5668864): hist 2MB (K0-K3) -> cand 3,145,728 (K4-K5)
//                       -> supp 4,096,000 (K6-K7) — disjoint lifetimes
// [5668864, 5675008): counts 8*192 u32
// [5675008, 5675520): cut, padded 16 u32 (64B) per batch
#define WS_SC   0
#define WS_PB   0
#define WS_PS   256000
#define WS_A    1572864
#define WS_CNT  5668864
#define WS_CUT  5675008

// ---------------- K0: zero histogram ----------------
__global__ void k_zero(unsigned int* __restrict__ hist) {
    int g = blockIdx.x * blockDim.x + threadIdx.x;
    if (g < BATCH * NBIN) hist[g] = 0u;
}

// ---------------- K1: fused softmax + 16-bit-key histogram ----------------
__global__ void k_softhist(const float* __restrict__ labels, float* __restrict__ scores,
                           unsigned int* __restrict__ hist) {
    int pos = blockIdx.x * blockDim.x + threadIdx.x;  // over BATCH*FH*FW
    if (pos >= BATCH * FHh * FWw) return;
    int b = pos / (FHh * FWw);
    const float* in = labels + (size_t)pos * NA;
    float v[NA];
    float m = in[0];
#pragma unroll
    for (int a = 0; a < NA; ++a) { v[a] = in[a]; m = fmaxf(m, v[a]); }
    float s = 0.0f;
#pragma unroll
    for (int a = 0; a < NA; ++a) { v[a] = expf(v[a] - m); s += v[a]; }
    float* o = scores + (size_t)pos * NA;
    unsigned int* hb = hist + (size_t)b * NBIN;
#pragma unroll
    for (int a = 0; a < NA; ++a) {
        float sc = v[a] / s;
        o[a] = sc;
        atomicAdd(&hb[__float_as_uint(sc) >> 16], 1u);  // fire-and-forget
    }
}

// ---------------- K2: per-batch find 16-bit cutoff bin ----------------
__global__ __launch_bounds__(1024) void k_cut(const unsigned int* __restrict__ hist,
                                              unsigned int* __restrict__ cut) {
    const int b = blockIdx.x;
    const int tid = threadIdx.x;
    const unsigned int* h = hist + (size_t)b * NBIN;
    const int base = NBIN - 1 - tid * 64;  // top bin of this thread's chunk
    unsigned int s = 0;
    for (int k = 0; k < 64; ++k) s += h[base - k];
    const int lane = tid & 63, wid = tid >> 6;
    unsigned int inc = s;
#pragma unroll
    for (int d = 1; d < 64; d <<= 1) {
        unsigned int v = __shfl_up(inc, d);
        if (lane >= d) inc += v;
    }
    __shared__ unsigned int wtot[16];
    if (lane == 63) wtot[wid] = inc;
    __syncthreads();
    unsigned int woff = 0;
    for (int w = 0; w < 16; ++w) if (w < wid) woff += wtot[w];
    unsigned int excl = woff + inc - s;  // count strictly above this chunk
    if (excl < PRE_K && excl + s >= PRE_K) {
        unsigned int run = excl;
        for (int k = 0; k < 64; ++k) {
            run += h[base - k];
            if (run >= PRE_K) { cut[b * 16] = (unsigned int)(base - k); break; }
        }
    }
}

// ------- K3: atomic-free gather. block = (batch b, segment kb of 256 anchors);
//         ballot-rank within block, private output segment. -------------------
__global__ __launch_bounds__(256) void k_gather(
        const float* __restrict__ scores, const unsigned int* __restrict__ cut,
        unsigned long long* __restrict__ cand, unsigned int* __restrict__ counts) {
    const int blk = blockIdx.x;
    const int b = blk / SEGS, kb = blk - b * SEGS;
    const int tid = threadIdx.x;
    __shared__ unsigned int s_cut;
    __shared__ unsigned int s_wcnt[4];
    if (tid == 0) s_cut = cut[b * 16];
    __syncthreads();
    const int idx = kb * 256 + tid;                       // batch-local anchor
    const unsigned int bits = __float_as_uint(scores[(size_t)b * NANCH + idx]);
    const bool pass = (bits >> 16) >= s_cut;
    const unsigned long long m = __ballot(pass);
    const int lane = tid & 63, w = tid >> 6;
    if (lane == 0) s_wcnt[w] = (unsigned int)__popcll(m);
    __syncthreads();
    unsigned int pre = 0, tot = 0;
#pragma unroll
    for (int i = 0; i < 4; ++i) { unsigned int c = s_wcnt[i]; if (i < w) pre += c; tot += c; }
    if (pass) {
        unsigned int rank = pre + (unsigned int)__popcll(m & ((1ull << lane) - 1ull));
        cand[((size_t)b * SEGS + kb) * 256 + rank] =
            ((unsigned long long)bits << 32) | (unsigned int)(~idx);
    }
    if (tid == 0) counts[b * SEGS + kb] = tot;
}

// ---- K4: per-batch compact segments -> bitonic sort 4096 -> decode top-2000 --
__global__ __launch_bounds__(1024) void k_sortdec(
        const unsigned long long* __restrict__ cand, const unsigned int* __restrict__ counts,
        const float* __restrict__ deltas, const float* __restrict__ anchors,
        float4* __restrict__ pre_boxes, float* __restrict__ pre_scores) {
    const int b = blockIdx.x;
    const int tid = threadIdx.x;
    __shared__ unsigned long long skey[SKEYN];
    __shared__ unsigned int s_wsum[3];
    for (int i = tid; i < SKEYN; i += 1024) skey[i] = 0ull;

    // scan the 192 per-segment counts (3 waves)
    unsigned int v = (tid < SEGS) ? counts[b * SEGS + tid] : 0u;
    const int lane = tid & 63, wid = tid >> 6;
    unsigned int inc = v;
#pragma unroll
    for (int d = 1; d < 64; d <<= 1) {
        unsigned int t = __shfl_up(inc, d);
        if (lane >= d) inc += t;
    }
    if (wid < 3 && lane == 63) s_wsum[wid] = inc;
    __syncthreads();
    if (tid < SEGS) {
        unsigned int woff = 0;
        for (int i = 0; i < wid; ++i) woff += s_wsum[i];
        unsigned int off = woff + inc - v;  // exclusive prefix
        const unsigned long long* seg = cand + ((size_t)b * SEGS + tid) * 256;
        for (unsigned int k = 0; k < v; ++k) {
            unsigned int p = off + k;
            if (p < SKEYN) skey[p] = seg[k];
        }
    }
    __syncthreads();

    // bitonic sort 4096 descending
    for (int k = 2; k <= SKEYN; k <<= 1) {
        for (int j = k >> 1; j > 0; j >>= 1) {
            for (int i = tid; i < SKEYN; i += 1024) {
                int p = i ^ j;
                if (p > i) {
                    unsigned long long a = skey[i], c = skey[p];
                    bool up = ((i & k) == 0);
                    if ((a < c) == up) { skey[i] = c; skey[p] = a; }
                }
            }
            __syncthreads();
        }
    }

    // decode the selected 2000 boxes (same op order as reference)
    for (int t = tid; t < PRE_K; t += 1024) {
        unsigned long long key = skey[t];
        int idx = (int)(~(unsigned int)key);
        float score = __uint_as_float((unsigned int)(key >> 32));
        const float* anc = anchors + (size_t)idx * 4;
        const float* del = deltas + ((size_t)b * NANCH + idx) * 4;
        float a0 = anc[0], a1 = anc[1], a2 = anc[2], a3 = anc[3];
        float ah = a2 - a0, aw = a3 - a1;
        float acy = a0 + 0.5f * ah, acx = a1 + 0.5f * aw;
        float d0 = del[0] * 0.1f, d1 = del[1] * 0.1f;
        float d2 = del[2] * 0.2f, d3 = del[3] * 0.2f;
        float bh = expf(d2) * ah, bw = expf(d3) * aw;
        float bcy = d0 * ah + acy, bcx = d1 * aw + acx;
        float y1 = bcy - 0.5f * bh, x1 = bcx - 0.5f * bw;
        pre_boxes[(size_t)b * PRE_K + t] = make_float4(y1, x1, y1 + bh, x1 + bw);
        pre_scores[(size_t)b * PRE_K + t] = score;
    }
}

// ---------------- K5: suppression bit-matrix (LDS-staged cols) ----------------
__global__ __launch_bounds__(64) void k_iou(const float4* __restrict__ pre_boxes,
                                            unsigned long long* __restrict__ supp) {
    const int cb = blockIdx.x;   // col word 0..31
    const int rb = blockIdx.y;   // row block 0..31
    const int b  = blockIdx.z;
    const int lane = threadIdx.x;
    const int i = rb * 64 + lane;
    const int j0 = cb * 64;
    if (cb < rb) {
        if (i < PRE_K) supp[((size_t)b * PRE_K + i) * 32 + cb] = 0ull;
        return;
    }
    __shared__ float4 sbox[64];
    const float4* boxes = pre_boxes + (size_t)b * PRE_K;
    int j = j0 + lane;
    sbox[lane] = (j < PRE_K) ? boxes[j] : make_float4(0.f, 0.f, 0.f, 0.f);
    __syncthreads();
    if (i >= PRE_K) return;
    float4 bi = boxes[i];
    float area_i = (bi.z - bi.x) * (bi.w - bi.y);
    unsigned long long bits = 0ull;
    const int tmax = (PRE_K - j0 < 64) ? (PRE_K - j0) : 64;
    for (int t = 0; t < tmax; ++t) {
        int jj = j0 + t;
        if (jj <= i) continue;
        float4 bj = sbox[t];
        float iy1 = fmaxf(bi.x, bj.x), ix1 = fmaxf(bi.y, bj.y);
        float iy2 = fminf(bi.z, bj.z), ix2 = fminf(bi.w, bj.w);
        float inter = fmaxf(iy2 - iy1, 0.0f) * fmaxf(ix2 - ix1, 0.0f);
        float area_j = (bj.z - bj.x) * (bj.w - bj.y);
        float uni = area_i + area_j - inter;
        float iou = inter / fmaxf(uni, 1e-8f);
        if (iou > 0.7f) bits |= (1ull << t);
    }
    supp[((size_t)b * PRE_K + i) * 32 + cb] = bits;
}

// ---------------- K6: serial greedy reduce + compact + outputs ----------------
// Scalar alive-word walk: cur (wave-uniform) holds the current 64-row word's
// keep bits; per-16-row chunk fast path when no intra-word suppression.
#define CHNK 16
__device__ __forceinline__ unsigned long long readlane64(unsigned long long x, int ln) {
    unsigned int lo = __builtin_amdgcn_readlane((unsigned int)x, ln);
    unsigned int hi = __builtin_amdgcn_readlane((unsigned int)(x >> 32), ln);
    return ((unsigned long long)hi << 32) | (unsigned long long)lo;
}
__global__ void k_final(const unsigned long long* __restrict__ supp,
                        const float4* __restrict__ pre_boxes,
                        const float* __restrict__ pre_scores,
                        float* __restrict__ out) {
    const int b = blockIdx.x;
    const int lane = threadIdx.x;
    float* ob = out + (size_t)b * POST_K * 4;
    float* os = out + (size_t)BATCH * POST_K * 4 + (size_t)b * POST_K;
    for (int t = lane; t < POST_K * 4; t += 64) ob[t] = 0.0f;
    for (int t = lane; t < POST_K; t += 64) os[t] = 0.0f;

    const unsigned long long* S = supp + (size_t)b * PRE_K * 32;
    const int lw = lane & 31;
    unsigned long long r0 = 0ull, r1 = 0ull;    // removed, two accumulators
    unsigned long long cur = ~0ull;             // alive bits of current word
    unsigned long long bufA[CHNK], bufB[CHNK];
#pragma unroll
    for (int c = 0; c < CHNK; ++c) bufA[c] = S[(size_t)c * 32 + lw];
    const int NCH = PRE_K / CHNK;  // 125
    for (int ch = 0; ch < NCH; ++ch) {
        const int base = ch * CHNK;
        if (ch + 1 < NCH) {
#pragma unroll
            for (int c = 0; c < CHNK; ++c)
                bufB[c] = S[(size_t)(base + CHNK + c) * 32 + lw];
        }
        const int wi = base >> 6;
        const int b0 = base & 63;
        if (b0 == 0) cur = ~readlane64(r0 | r1, wi);  // word boundary refresh
        // OR-tree of this chunk's 16 rows (off critical chain)
        unsigned long long t0 = (bufA[0] | bufA[1]) | (bufA[2] | bufA[3]);
        unsigned long long t1 = (bufA[4] | bufA[5]) | (bufA[6] | bufA[7]);
        unsigned long long t2 = (bufA[8] | bufA[9]) | (bufA[10] | bufA[11]);
        unsigned long long t3 = (bufA[12] | bufA[13]) | (bufA[14] | bufA[15]);
        unsigned long long tor = (t0 | t1) | (t2 | t3);
        unsigned long long intra = readlane64(tor, wi);
        if (intra == 0ull) {
            // fast: no row of this chunk suppresses anything in its own word,
            // so cur is invariant across the chunk -> branchless masked ORs.
#pragma unroll
            for (int c = 0; c < CHNK; ++c) {
                unsigned long long msk =
                    ((cur >> (b0 + c)) & 1ull) ? ~0ull : 0ull;
                if (c & 1) r1 |= bufA[c] & msk; else r0 |= bufA[c] & msk;
            }
        } else {
            // slow: exact per-row walk; diagonal word lives in lane wi of bufA
#pragma unroll
            for (int c = 0; c < CHNK; ++c) {
                const int bi = b0 + c;
                if ((cur >> bi) & 1ull) {
                    cur &= ~readlane64(bufA[c], wi);
                    if (c & 1) r1 |= bufA[c]; else r0 |= bufA[c];
                }
            }
        }
#pragma unroll
        for (int c = 0; c < CHNK; ++c) bufA[c] = bufB[c];
    }
    const unsigned long long removed = r0 | r1;

    // compact kept rows in order -> first POST_K outputs
    unsigned long long kw = ~removed;
    if (lw == 31) kw &= 0xFFFFull;  // rows 1984..1999 only
    int cnt = (lane < 32) ? __builtin_popcountll(kw) : 0;
    int cum = cnt;
#pragma unroll
    for (int d = 1; d < 64; d <<= 1) {
        int v = __shfl_up(cum, d);
        if (lane >= d) cum += v;
    }
    int r = cum - cnt;
    __syncthreads();
    if (lane < 32) {
        unsigned long long m = kw;
        while (m != 0ull && r < POST_K) {
            int t = __builtin_ctzll(m);
            m &= m - 1ull;
            int i = lw * 64 + t;
            float4 bx = pre_boxes[(size_t)b * PRE_K + i];
            ob[r * 4 + 0] = fminf(fmaxf(bx.x, 0.0f), 1.0f);
            ob[r * 4 + 1] = fminf(fmaxf(bx.y, 0.0f), 1.0f);
            ob[r * 4 + 2] = fminf(fmaxf(bx.z, 0.0f), 1.0f);
            ob[r * 4 + 3] = fminf(fmaxf(bx.w, 0.0f), 1.0f);
            os[r] = pre_scores[(size_t)b * PRE_K + i];
            ++r;
        }
    }
}

extern "C" void kernel_launch(void* const* d_in, const int* in_sizes, int n_in,
                              void* d_out, int out_size, void* d_ws, size_t ws_size,
                              hipStream_t stream) {
    const float* deltas  = (const float*)d_in[0];
    const float* labels  = (const float*)d_in[1];
    const float* anchors = (const float*)d_in[2];
    float* out = (float*)d_out;

    char* ws = (char*)d_ws;
    float* scores          = (float*)(ws + WS_SC);
    unsigned int* hist     = (unsigned int*)(ws + WS_A);
    unsigned long long* cd = (unsigned long long*)(ws + WS_A);   // reuses hist
    unsigned long long* sp = (unsigned long long*)(ws + WS_A);   // reuses cand
    unsigned int* cntp     = (unsigned int*)(ws + WS_CNT);
    unsigned int* cutp     = (unsigned int*)(ws + WS_CUT);
    float4* pre_boxes      = (float4*)(ws + WS_PB);              // reuses scores
    float* pre_scores      = (float*)(ws + WS_PS);

    k_zero<<<(BATCH * NBIN + 255) / 256, 256, 0, stream>>>(hist);
    k_softhist<<<(BATCH * FHh * FWw + 255) / 256, 256, 0, stream>>>(labels, scores, hist);
    k_cut<<<BATCH, 1024, 0, stream>>>(hist, cutp);
    k_gather<<<BATCH * SEGS, 256, 0, stream>>>(scores, cutp, cd, cntp);
    k_sortdec<<<BATCH, 1024, 0, stream>>>(cd, cntp, deltas, anchors, pre_boxes, pre_scores);
    k_iou<<<dim3(32, 32, BATCH), 64, 0, stream>>>(pre_boxes, sp);
    k_final<<<BATCH, 64, 0, stream>>>(sp, pre_boxes, pre_scores, out);
}

// Round 5
// 193.528 us; speedup vs baseline: 2.1566x; 1.0696x over previous
//
#include <hip/hip_runtime.h>
#include <cstdint>
#include <cstddef>

#define BATCH 8
#define FHh   32
#define FWw   256
#define NA    6
#define NANCH (FHh * FWw * NA)   // 49152
#define PRE_K 2000
#define POST_K 300
#define NBIN  65536
#define SEGS  192                // blocks per batch in k_gather (NANCH/256)
#define SKEYN 4096

typedef unsigned long long u64;

// ---------------- workspace layout (bytes), total 5,675,520 ----------------
// [0, 1572864)      : scores (K1-K4); then pre_boxes [0,256000) +
//                     pre_scores [256000,320000) (K5-K7) — disjoint lifetime
// A=[1572864, 5668864): hist 2MB (K0-K3) -> cand 3,145,728 (K4-K5)
//                       -> supp 4,096,000 (K6-K7) — disjoint lifetimes
// [5668864, 5675008): counts 8*192 u32
// [5675008, 5675520): cut, padded 16 u32 (64B) per batch
#define WS_SC   0
#define WS_PB   0
#define WS_PS   256000
#define WS_A    1572864
#define WS_CNT  5668864
#define WS_CUT  5675008

// ---------------- K0: zero histogram ----------------
__global__ void k_zero(unsigned int* __restrict__ hist) {
    int g = blockIdx.x * blockDim.x + threadIdx.x;
    if (g < BATCH * NBIN) hist[g] = 0u;
}

// ---------------- K1: fused softmax + 16-bit-key histogram ----------------
__global__ void k_softhist(const float* __restrict__ labels, float* __restrict__ scores,
                           unsigned int* __restrict__ hist) {
    int pos = blockIdx.x * blockDim.x + threadIdx.x;  // over BATCH*FH*FW
    if (pos >= BATCH * FHh * FWw) return;
    int b = pos / (FHh * FWw);
    const float* in = labels + (size_t)pos * NA;
    float v[NA];
    float m = in[0];
#pragma unroll
    for (int a = 0; a < NA; ++a) { v[a] = in[a]; m = fmaxf(m, v[a]); }
    float s = 0.0f;
#pragma unroll
    for (int a = 0; a < NA; ++a) { v[a] = expf(v[a] - m); s += v[a]; }
    float* o = scores + (size_t)pos * NA;
    unsigned int* hb = hist + (size_t)b * NBIN;
#pragma unroll
    for (int a = 0; a < NA; ++a) {
        float sc = v[a] / s;
        o[a] = sc;
        atomicAdd(&hb[__float_as_uint(sc) >> 16], 1u);  // fire-and-forget
    }
}

// ---------------- K2: per-batch find 16-bit cutoff bin ----------------
__global__ __launch_bounds__(1024) void k_cut(const unsigned int* __restrict__ hist,
                                              unsigned int* __restrict__ cut) {
    const int b = blockIdx.x;
    const int tid = threadIdx.x;
    const unsigned int* h = hist + (size_t)b * NBIN;
    const int base = NBIN - 1 - tid * 64;  // top bin of this thread's chunk
    unsigned int s = 0;
    for (int k = 0; k < 64; ++k) s += h[base - k];
    const int lane = tid & 63, wid = tid >> 6;
    unsigned int inc = s;
#pragma unroll
    for (int d = 1; d < 64; d <<= 1) {
        unsigned int v = __shfl_up(inc, d);
        if (lane >= d) inc += v;
    }
    __shared__ unsigned int wtot[16];
    if (lane == 63) wtot[wid] = inc;
    __syncthreads();
    unsigned int woff = 0;
    for (int w = 0; w < 16; ++w) if (w < wid) woff += wtot[w];
    unsigned int excl = woff + inc - s;  // count strictly above this chunk
    if (excl < PRE_K && excl + s >= PRE_K) {
        unsigned int run = excl;
        for (int k = 0; k < 64; ++k) {
            run += h[base - k];
            if (run >= PRE_K) { cut[b * 16] = (unsigned int)(base - k); break; }
        }
    }
}

// ------- K3: atomic-free gather. block = (batch b, segment kb of 256 anchors);
//         ballot-rank within block, private output segment. -------------------
__global__ __launch_bounds__(256) void k_gather(
        const float* __restrict__ scores, const unsigned int* __restrict__ cut,
        u64* __restrict__ cand, unsigned int* __restrict__ counts) {
    const int blk = blockIdx.x;
    const int b = blk / SEGS, kb = blk - b * SEGS;
    const int tid = threadIdx.x;
    __shared__ unsigned int s_cut;
    __shared__ unsigned int s_wcnt[4];
    if (tid == 0) s_cut = cut[b * 16];
    __syncthreads();
    const int idx = kb * 256 + tid;                       // batch-local anchor
    const unsigned int bits = __float_as_uint(scores[(size_t)b * NANCH + idx]);
    const bool pass = (bits >> 16) >= s_cut;
    const u64 m = __ballot(pass);
    const int lane = tid & 63, w = tid >> 6;
    if (lane == 0) s_wcnt[w] = (unsigned int)__popcll(m);
    __syncthreads();
    unsigned int pre = 0, tot = 0;
#pragma unroll
    for (int i = 0; i < 4; ++i) { unsigned int c = s_wcnt[i]; if (i < w) pre += c; tot += c; }
    if (pass) {
        unsigned int rank = pre + (unsigned int)__popcll(m & ((1ull << lane) - 1ull));
        cand[((size_t)b * SEGS + kb) * 256 + rank] =
            ((u64)bits << 32) | (unsigned int)(~idx);
    }
    if (tid == 0) counts[b * SEGS + kb] = tot;
}

// ---- K4: per-batch compact segments -> bitonic sort 4096 -> decode top-2000 --
__global__ __launch_bounds__(1024) void k_sortdec(
        const u64* __restrict__ cand, const unsigned int* __restrict__ counts,
        const float* __restrict__ deltas, const float* __restrict__ anchors,
        float4* __restrict__ pre_boxes, float* __restrict__ pre_scores) {
    const int b = blockIdx.x;
    const int tid = threadIdx.x;
    __shared__ u64 skey[SKEYN];
    __shared__ unsigned int s_wsum[3];
    for (int i = tid; i < SKEYN; i += 1024) skey[i] = 0ull;

    // scan the 192 per-segment counts (3 waves)
    unsigned int v = (tid < SEGS) ? counts[b * SEGS + tid] : 0u;
    const int lane = tid & 63, wid = tid >> 6;
    unsigned int inc = v;
#pragma unroll
    for (int d = 1; d < 64; d <<= 1) {
        unsigned int t = __shfl_up(inc, d);
        if (lane >= d) inc += t;
    }
    if (wid < 3 && lane == 63) s_wsum[wid] = inc;
    __syncthreads();
    if (tid < SEGS) {
        unsigned int woff = 0;
        for (int i = 0; i < wid; ++i) woff += s_wsum[i];
        unsigned int off = woff + inc - v;  // exclusive prefix
        const u64* seg = cand + ((size_t)b * SEGS + tid) * 256;
        for (unsigned int k = 0; k < v; ++k) {
            unsigned int p = off + k;
            if (p < SKEYN) skey[p] = seg[k];
        }
    }
    __syncthreads();

    // bitonic sort 4096 descending
    for (int k = 2; k <= SKEYN; k <<= 1) {
        for (int j = k >> 1; j > 0; j >>= 1) {
            for (int i = tid; i < SKEYN; i += 1024) {
                int p = i ^ j;
                if (p > i) {
                    u64 a = skey[i], c = skey[p];
                    bool up = ((i & k) == 0);
                    if ((a < c) == up) { skey[i] = c; skey[p] = a; }
                }
            }
            __syncthreads();
        }
    }

    // decode the selected 2000 boxes (same op order as reference)
    for (int t = tid; t < PRE_K; t += 1024) {
        u64 key = skey[t];
        int idx = (int)(~(unsigned int)key);
        float score = __uint_as_float((unsigned int)(key >> 32));
        const float* anc = anchors + (size_t)idx * 4;
        const float* del = deltas + ((size_t)b * NANCH + idx) * 4;
        float a0 = anc[0], a1 = anc[1], a2 = anc[2], a3 = anc[3];
        float ah = a2 - a0, aw = a3 - a1;
        float acy = a0 + 0.5f * ah, acx = a1 + 0.5f * aw;
        float d0 = del[0] * 0.1f, d1 = del[1] * 0.1f;
        float d2 = del[2] * 0.2f, d3 = del[3] * 0.2f;
        float bh = expf(d2) * ah, bw = expf(d3) * aw;
        float bcy = d0 * ah + acy, bcx = d1 * aw + acx;
        float y1 = bcy - 0.5f * bh, x1 = bcx - 0.5f * bw;
        pre_boxes[(size_t)b * PRE_K + t] = make_float4(y1, x1, y1 + bh, x1 + bw);
        pre_scores[(size_t)b * PRE_K + t] = score;
    }
}

// ---------------- K5: suppression bit-matrix (LDS-staged cols) ----------------
__global__ __launch_bounds__(64) void k_iou(const float4* __restrict__ pre_boxes,
                                            u64* __restrict__ supp) {
    const int cb = blockIdx.x;   // col word 0..31
    const int rb = blockIdx.y;   // row block 0..31
    const int b  = blockIdx.z;
    const int lane = threadIdx.x;
    const int i = rb * 64 + lane;
    const int j0 = cb * 64;
    if (cb < rb) {
        if (i < PRE_K) supp[((size_t)b * PRE_K + i) * 32 + cb] = 0ull;
        return;
    }
    __shared__ float4 sbox[64];
    const float4* boxes = pre_boxes + (size_t)b * PRE_K;
    int j = j0 + lane;
    sbox[lane] = (j < PRE_K) ? boxes[j] : make_float4(0.f, 0.f, 0.f, 0.f);
    __syncthreads();
    if (i >= PRE_K) return;
    float4 bi = boxes[i];
    float area_i = (bi.z - bi.x) * (bi.w - bi.y);
    u64 bits = 0ull;
    const int tmax = (PRE_K - j0 < 64) ? (PRE_K - j0) : 64;
    for (int t = 0; t < tmax; ++t) {
        int jj = j0 + t;
        if (jj <= i) continue;
        float4 bj = sbox[t];
        float iy1 = fmaxf(bi.x, bj.x), ix1 = fmaxf(bi.y, bj.y);
        float iy2 = fminf(bi.z, bj.z), ix2 = fminf(bi.w, bj.w);
        float inter = fmaxf(iy2 - iy1, 0.0f) * fmaxf(ix2 - ix1, 0.0f);
        float area_j = (bj.z - bj.x) * (bj.w - bj.y);
        float uni = area_i + area_j - inter;
        float iou = inter / fmaxf(uni, 1e-8f);
        if (iou > 0.7f) bits |= (1ull << t);
    }
    supp[((size_t)b * PRE_K + i) * 32 + cb] = bits;
}

// ---------------- K6: serial greedy reduce + compact + outputs ----------------
// 64-row word epochs, 2-buffer ping-pong (no copies), fast/slow per 16-row
// subgroup. cur = wave-uniform alive word (SGPRs); single wave per block.
__device__ __forceinline__ u64 readlane64(u64 x, int ln) {
    unsigned int lo = __builtin_amdgcn_readlane((unsigned int)x, ln);
    unsigned int hi = __builtin_amdgcn_readlane((unsigned int)(x >> 32), ln);
    return ((u64)hi << 32) | (u64)lo;
}

template <int NR>
__device__ __forceinline__ void load_chunk(u64* __restrict__ buf,
        const u64* __restrict__ S, int base, int lw) {
#pragma unroll
    for (int c = 0; c < NR; ++c)
        buf[c] = S[(size_t)(base + c) * 32 + lw];
}

// wi = word index (= base>>6, base word-aligned). cur refreshed once per word.
template <int NR>
__device__ __forceinline__ void process_chunk(const u64* __restrict__ buf,
        int wi, u64& r0, u64& r1, u64& cur) {
    cur = ~readlane64(r0 | r1, wi);
#pragma unroll
    for (int g = 0; g < NR / 16; ++g) {
        const int b0 = g * 16;
        u64 t0 = (buf[b0+0] | buf[b0+1]) | (buf[b0+2] | buf[b0+3]);
        u64 t1 = (buf[b0+4] | buf[b0+5]) | (buf[b0+6] | buf[b0+7]);
        u64 t2 = (buf[b0+8] | buf[b0+9]) | (buf[b0+10] | buf[b0+11]);
        u64 t3 = (buf[b0+12] | buf[b0+13]) | (buf[b0+14] | buf[b0+15]);
        u64 tor = (t0 | t1) | (t2 | t3);
        u64 intra = readlane64(tor, wi);
        if (intra == 0ull) {
            // no row of this subgroup suppresses anything in word wi ->
            // cur invariant across subgroup -> branchless masked ORs
#pragma unroll
            for (int c = 0; c < 16; ++c) {
                u64 msk = ((cur >> (b0 + c)) & 1ull) ? ~0ull : 0ull;
                if (c & 1) r1 |= buf[b0+c] & msk; else r0 |= buf[b0+c] & msk;
            }
        } else {
            // exact per-row walk; wave-uniform branches (SALU)
#pragma unroll
            for (int c = 0; c < 16; ++c) {
                if ((cur >> (b0 + c)) & 1ull) {
                    cur &= ~readlane64(buf[b0+c], wi);
                    if (c & 1) r1 |= buf[b0+c]; else r0 |= buf[b0+c];
                }
            }
        }
    }
}

__global__ __launch_bounds__(64) void k_final(const u64* __restrict__ supp,
                        const float4* __restrict__ pre_boxes,
                        const float* __restrict__ pre_scores,
                        float* __restrict__ out) {
    const int b = blockIdx.x;
    const int lane = threadIdx.x;
    float* ob = out + (size_t)b * POST_K * 4;
    float* os = out + (size_t)BATCH * POST_K * 4 + (size_t)b * POST_K;
    for (int t = lane; t < POST_K * 4; t += 64) ob[t] = 0.0f;
    for (int t = lane; t < POST_K; t += 64) os[t] = 0.0f;

    const u64* S = supp + (size_t)b * PRE_K * 32;
    const int lw = lane & 31;
    u64 r0 = 0ull, r1 = 0ull, cur = ~0ull;
    u64 A[64], B[64];
    load_chunk<64>(A, S, 0, lw);
    // 2000 rows = 31 full 64-row words (0..30) + 16-row tail (word 31)
    for (int ch = 0; ch < 30; ch += 2) {
        load_chunk<64>(B, S, (ch + 1) * 64, lw);
        process_chunk<64>(A, ch, r0, r1, cur);
        load_chunk<64>(A, S, (ch + 2) * 64, lw);
        process_chunk<64>(B, ch + 1, r0, r1, cur);
    }
    // A holds word 30; prefetch tail then drain
    load_chunk<16>(B, S, 31 * 64, lw);
    process_chunk<64>(A, 30, r0, r1, cur);
    process_chunk<16>(B, 31, r0, r1, cur);
    const u64 removed = r0 | r1;

    // compact kept rows in order -> first POST_K outputs
    u64 kw = ~removed;
    if (lw == 31) kw &= 0xFFFFull;  // rows 1984..1999 only
    int cnt = (lane < 32) ? __builtin_popcountll(kw) : 0;
    int cum = cnt;
#pragma unroll
    for (int d = 1; d < 64; d <<= 1) {
        int v = __shfl_up(cum, d);
        if (lane >= d) cum += v;
    }
    int r = cum - cnt;
    __syncthreads();
    if (lane < 32) {
        u64 m = kw;
        while (m != 0ull && r < POST_K) {
            int t = __builtin_ctzll(m);
            m &= m - 1ull;
            int i = lw * 64 + t;
            float4 bx = pre_boxes[(size_t)b * PRE_K + i];
            ob[r * 4 + 0] = fminf(fmaxf(bx.x, 0.0f), 1.0f);
            ob[r * 4 + 1] = fminf(fmaxf(bx.y, 0.0f), 1.0f);
            ob[r * 4 + 2] = fminf(fmaxf(bx.z, 0.0f), 1.0f);
            ob[r * 4 + 3] = fminf(fmaxf(bx.w, 0.0f), 1.0f);
            os[r] = pre_scores[(size_t)b * PRE_K + i];
            ++r;
        }
    }
}

extern "C" void kernel_launch(void* const* d_in, const int* in_sizes, int n_in,
                              void* d_out, int out_size, void* d_ws, size_t ws_size,
                              hipStream_t stream) {
    const float* deltas  = (const float*)d_in[0];
    const float* labels  = (const float*)d_in[1];
    const float* anchors = (const float*)d_in[2];
    float* out = (float*)d_out;

    char* ws = (char*)d_ws;
    float* scores          = (float*)(ws + WS_SC);
    unsigned int* hist     = (unsigned int*)(ws + WS_A);
    u64* cd                = (u64*)(ws + WS_A);   // reuses hist
    u64* sp                = (u64*)(ws + WS_A);   // reuses cand
    unsigned int* cntp     = (unsigned int*)(ws + WS_CNT);
    unsigned int* cutp     = (unsigned int*)(ws + WS_CUT);
    float4* pre_boxes      = (float4*)(ws + WS_PB);              // reuses scores
    float* pre_scores      = (float*)(ws + WS_PS);

    k_zero<<<(BATCH * NBIN + 255) / 256, 256, 0, stream>>>(hist);
    k_softhist<<<(BATCH * FHh * FWw + 255) / 256, 256, 0, stream>>>(labels, scores, hist);
    k_cut<<<BATCH, 1024, 0, stream>>>(hist, cutp);
    k_gather<<<BATCH * SEGS, 256, 0, stream>>>(scores, cutp, cd, cntp);
    k_sortdec<<<BATCH, 1024, 0, stream>>>(cd, cntp, deltas, anchors, pre_boxes, pre_scores);
    k_iou<<<dim3(32, 32, BATCH), 64, 0, stream>>>(pre_boxes, sp);
    k_final<<<BATCH, 64, 0, stream>>>(sp, pre_boxes, pre_scores, out);
}